// Round 4
// baseline (546.555 us; speedup 1.0000x reference)
//
#include <hip/hip_runtime.h>
#include <stdint.h>

#define DEVI __device__ __forceinline__

typedef __bf16 bf16x8 __attribute__((ext_vector_type(8)));
typedef float  floatx4 __attribute__((ext_vector_type(4)));

// B=8, S=2048, H=1024. M = B*S = 16384.
// ws: Q @0 (32MiB, pre-scaled 1/32) | K @+32M | Vt @+64M ([8][1024 d][2048 k])
//     lvec @+96M (f32[16384]) | P @+96M+64K (bf16 [8][2048][2048]);
//     P region overlays Xb (32MiB) + Wt (6MiB), dead before P written.

DEVI unsigned short f2bf(float f) {
  union { float f; uint32_t u; } x; x.f = f;
  return (unsigned short)((x.u + 0x7fffu + ((x.u >> 16) & 1u)) >> 16);
}
DEVI float bf2f(unsigned short s) {
  union { uint32_t u; float f; } x; x.u = ((uint32_t)s) << 16;
  return x.f;
}

// ---------------- fused prep: X->bf16, 3x W transpose->bf16, lvec=0 ----------------
__global__ __launch_bounds__(256) void k_prep(
    const float* __restrict__ X, unsigned short* __restrict__ Xb,
    const float* __restrict__ Wq, const float* __restrict__ Wk,
    const float* __restrict__ Wv, unsigned short* __restrict__ Wt,
    float* __restrict__ lvec) {
  __shared__ float tile[64][65];
  int bx = blockIdx.x, t = threadIdx.x;
  if (bx < 16384) {                 // convert X: 4194304 float4 groups
    int i = bx * 256 + t;
    float4 v = ((const float4*)X)[i];
    ushort4 o;
    o.x = f2bf(v.x); o.y = f2bf(v.y); o.z = f2bf(v.z); o.w = f2bf(v.w);
    ((ushort4*)Xb)[i] = o;
  } else if (bx < 17152) {          // 3 x 256 transpose blocks
    int idx = bx - 16384;
    int sel = idx >> 8, b2 = idx & 255;
    const float* W = sel == 0 ? Wq : (sel == 1 ? Wk : Wv);
    unsigned short* Wo = Wt + ((size_t)sel << 20);
    int h0 = (b2 & 15) * 64, d0 = (b2 >> 4) * 64;
#pragma unroll
    for (int i = 0; i < 16; ++i) {
      int idx2 = i * 256 + t; int r = idx2 >> 6, c = idx2 & 63;
      tile[r][c] = W[(size_t)(h0 + r) * 1024 + d0 + c];
    }
    __syncthreads();
#pragma unroll
    for (int i = 0; i < 16; ++i) {
      int idx2 = i * 256 + t; int r = idx2 >> 6, c = idx2 & 63;
      Wo[(size_t)(d0 + r) * 1024 + h0 + c] = f2bf(tile[c][r]);
    }
  } else {                          // zero lvec (16384 f32)
    float4 z4 = {0.f, 0.f, 0.f, 0.f};
#pragma unroll
    for (int i = 0; i < 16; ++i) ((float4*)lvec)[i * 256 + t] = z4;
  }
}

// ---------------- async 16B global -> LDS ----------------
DEVI void gl_lds16(const unsigned short* gp, unsigned short* lp) {
  __builtin_amdgcn_global_load_lds(
      (const __attribute__((address_space(1))) void*)gp,
      (__attribute__((address_space(3))) void*)lp, 16, 0, 0);
}

// ---------------- C = A * Bt^T  (both bf16 row-major, K-major rows) ----------------
// 128x128 tile, BK=64, 4 waves, 16x MFMA 16x16x32 per wave quadrant.
// LDS 16B-unit XOR swizzle c' = c ^ (row&7).
// EPI: 4 = fused QKV (sel=blockIdx.y>>3): Q (x+b)/32, K x+b, V -> Vt[b][d][k].
//          B (=Wt, 2 MiB/sel, L2-resident) is loaded DIRECTLY global->VGPR,
//          no LDS staging: halves LDS-pipe traffic, loads hoist past barrier.
//      2 = P = exp(S) masked, bf16; atomic row sums -> lsum
//      3 = O = (P*V) * 1/lvec[row], f32
template <int EPI>
__global__ __launch_bounds__(256) void k_gemm(
    const unsigned short* __restrict__ A, const unsigned short* __restrict__ Bt,
    void* __restrict__ Cv,
    const float* __restrict__ bias_q, const float* __restrict__ bias_k,
    const float* __restrict__ bias_v,
    const float* __restrict__ lvec, float* __restrict__ lsum,
    const int* __restrict__ mask,
    long aZ, long bZ, int ldA, int ldB, int kIters)
{
  __shared__ unsigned short As[128 * 64];
  __shared__ unsigned short Bs[(EPI == 4) ? 16 : 128 * 64];
  const int t = threadIdx.x, w = t >> 6, l = t & 63;
  const int quad = l >> 4, l15 = l & 15;
  const int m0 = blockIdx.x * 128;
  const int z = blockIdx.z;
  const int wm = (w & 1) * 64, wn = (w >> 1) * 64;

  int n0, sel = 0;
  if constexpr (EPI == 4) { sel = blockIdx.y >> 3; n0 = (blockIdx.y & 7) * 128; }
  else n0 = blockIdx.y * 128;

  const unsigned short* Az = A + (size_t)z * aZ;
  const unsigned short* Bz = (EPI == 4) ? (Bt + ((size_t)sel << 20))
                                        : (Bt + (size_t)z * bZ);

  floatx4 acc[4][4];
#pragma unroll
  for (int i = 0; i < 4; ++i)
#pragma unroll
    for (int j = 0; j < 4; ++j) { floatx4 zz = {0.f, 0.f, 0.f, 0.f}; acc[i][j] = zz; }

  for (int kt = 0; kt < kIters; ++kt) {
    if constexpr (EPI == 4) {
      // B frags straight from global (L2-hot Wt); no barrier dependency.
      bf16x8 bfr2[2][4];
#pragma unroll
      for (int ks = 0; ks < 2; ++ks)
#pragma unroll
        for (int ns = 0; ns < 4; ++ns)
          bfr2[ks][ns] = *(const bf16x8*)(
              Bz + (size_t)(n0 + wn + ns * 16 + l15) * 1024
                 + kt * 64 + ks * 32 + quad * 8);
      __syncthreads();
#pragma unroll
      for (int i = 0; i < 4; ++i) {
        int u   = (i * 4 + w) * 64 + l;   // 16B-unit index in [0,1024)
        int row = u >> 3;
        int cc  = (u & 7) ^ (row & 7);
        gl_lds16(Az + (size_t)(m0 + row) * ldA + kt * 64 + cc * 8,
                 &As[(i * 4 + w) * 512]);
      }
      __syncthreads();
#pragma unroll
      for (int ks = 0; ks < 2; ++ks) {
        bf16x8 af[4];
#pragma unroll
        for (int ms = 0; ms < 4; ++ms) {
          int r  = wm + ms * 16 + l15;          // A[m=lane&15][k=quad*8+j]
          int cc = (ks * 4 + quad) ^ (r & 7);
          af[ms] = *(const bf16x8*)&As[r * 64 + cc * 8];
        }
#pragma unroll
        for (int ms = 0; ms < 4; ++ms)
#pragma unroll
          for (int ns = 0; ns < 4; ++ns)
            acc[ms][ns] = __builtin_amdgcn_mfma_f32_16x16x32_bf16(
                af[ms], bfr2[ks][ns], acc[ms][ns], 0, 0, 0);
      }
    } else {
      __syncthreads();
#pragma unroll
      for (int i = 0; i < 4; ++i) {
        int u   = (i * 4 + w) * 64 + l;
        int row = u >> 3;
        int cc  = (u & 7) ^ (row & 7);
        gl_lds16(Az + (size_t)(m0 + row) * ldA + kt * 64 + cc * 8,
                 &As[(i * 4 + w) * 512]);
        gl_lds16(Bz + (size_t)(n0 + row) * ldB + kt * 64 + cc * 8,
                 &Bs[(i * 4 + w) * 512]);
      }
      __syncthreads();
#pragma unroll
      for (int ks = 0; ks < 2; ++ks) {
        bf16x8 af[4], bfr[4];
#pragma unroll
        for (int ms = 0; ms < 4; ++ms) {
          int r  = wm + ms * 16 + l15;
          int cc = (ks * 4 + quad) ^ (r & 7);
          af[ms] = *(const bf16x8*)&As[r * 64 + cc * 8];
        }
#pragma unroll
        for (int ns = 0; ns < 4; ++ns) {
          int r  = wn + ns * 16 + l15;
          int cc = (ks * 4 + quad) ^ (r & 7);
          bfr[ns] = *(const bf16x8*)&Bs[r * 64 + cc * 8];
        }
#pragma unroll
        for (int ms = 0; ms < 4; ++ms)
#pragma unroll
          for (int ns = 0; ns < 4; ++ns)
            acc[ms][ns] = __builtin_amdgcn_mfma_f32_16x16x32_bf16(
                af[ms], bfr[ns], acc[ms][ns], 0, 0, 0);
      }
    }
  }

  // epilogue: C/D layout col = lane&15, row = quad*4 + reg  [m89/m91]
  if constexpr (EPI == 4) {
    unsigned short* C = (unsigned short*)Cv + ((size_t)sel << 24);
    const float* bs = sel == 0 ? bias_q : (sel == 1 ? bias_k : bias_v);
    if (sel < 2) {
      float sc = sel == 0 ? 0.03125f : 1.0f;
#pragma unroll
      for (int ns = 0; ns < 4; ++ns) {
        int n_g = n0 + wn + ns * 16 + l15;
        float bv = bs[n_g];
#pragma unroll
        for (int ms = 0; ms < 4; ++ms) {
          int mb = m0 + wm + ms * 16 + quad * 4;
#pragma unroll
          for (int r = 0; r < 4; ++r)
            C[(size_t)(mb + r) * 1024 + n_g] = f2bf((acc[ms][ns][r] + bv) * sc);
        }
      }
    } else {                             // V: transposed Vt[b][d][k]
#pragma unroll
      for (int ns = 0; ns < 4; ++ns) {
        int n_g = n0 + wn + ns * 16 + l15;
        float bv = bs[n_g];
#pragma unroll
        for (int ms = 0; ms < 4; ++ms) {
#pragma unroll
          for (int r = 0; r < 4; ++r) {
            int m_g = m0 + wm + ms * 16 + quad * 4 + r;
            int bb = m_g >> 11, key = m_g & 2047;
            C[((size_t)bb << 21) + ((size_t)n_g << 11) + key] =
                f2bf(acc[ms][ns][r] + bv);
          }
        }
      }
    }
  } else if constexpr (EPI == 2) {
    // P = exp(S) (max-free: |S| <= ~6), masked; atomic rowsums
    unsigned short* C = (unsigned short*)Cv + (size_t)z * 4194304;
    const int* mz = mask + z * 2048;
    float rowsum[4][4];
#pragma unroll
    for (int ms = 0; ms < 4; ++ms)
#pragma unroll
      for (int r = 0; r < 4; ++r) rowsum[ms][r] = 0.f;
#pragma unroll
    for (int ns = 0; ns < 4; ++ns) {
      int n_g = n0 + wn + ns * 16 + l15;
      int mv = mz[n_g];
#pragma unroll
      for (int ms = 0; ms < 4; ++ms) {
#pragma unroll
        for (int r = 0; r < 4; ++r) {
          int m_g = m0 + wm + ms * 16 + quad * 4 + r;
          float e = mv ? __expf(acc[ms][ns][r]) : 0.f;
          unsigned short pb = f2bf(e);
          C[(size_t)m_g * 2048 + n_g] = pb;
          rowsum[ms][r] += bf2f(pb);
        }
      }
    }
#pragma unroll
    for (int ms = 0; ms < 4; ++ms) {
#pragma unroll
      for (int r = 0; r < 4; ++r) {
        float s = rowsum[ms][r];
#pragma unroll
        for (int off = 1; off < 16; off <<= 1) s += __shfl_xor(s, off);
        if (l15 == 0) {
          int m_g = m0 + wm + ms * 16 + quad * 4 + r;
          atomicAdd(&lsum[z * 2048 + m_g], s);
        }
      }
    }
  } else {  // EPI == 3: O = (P*V)/l
    float* C = (float*)Cv + (size_t)z * 2048 * 1024;
    const float* lz = lvec + z * 2048;
#pragma unroll
    for (int ms = 0; ms < 4; ++ms) {
#pragma unroll
      for (int r = 0; r < 4; ++r) {
        int m_g = m0 + wm + ms * 16 + quad * 4 + r;
        float lw = lz[m_g];
        float inv = lw > 0.f ? 1.f / lw : 0.f;
#pragma unroll
        for (int ns = 0; ns < 4; ++ns) {
          int n_g = n0 + wn + ns * 16 + l15;
          C[(size_t)m_g * 1024 + n_g] = acc[ms][ns][r] * inv;
        }
      }
    }
  }
}

extern "C" void kernel_launch(void* const* d_in, const int* in_sizes, int n_in,
                              void* d_out, int out_size, void* d_ws, size_t ws_size,
                              hipStream_t stream) {
  const float* X    = (const float*)d_in[0];
  const int*   mask = (const int*)d_in[1];
  const float* Wq   = (const float*)d_in[2];
  const float* bq   = (const float*)d_in[3];
  const float* Wk   = (const float*)d_in[4];
  const float* bk   = (const float*)d_in[5];
  const float* Wv   = (const float*)d_in[6];
  const float* bv   = (const float*)d_in[7];
  float* out = (float*)d_out;

  constexpr size_t SZ = (size_t)16384 * 1024;
  unsigned short* Q    = (unsigned short*)d_ws;      // Q|K|Vt contiguous (sel<<24)
  float*          lvec = (float*)(Q + 3 * SZ);
  unsigned short* P    = (unsigned short*)(lvec + 16384);
  unsigned short* Xb   = P;               // overlaid: dead before P written
  unsigned short* Wt   = Xb + SZ;         // 3 x [1024][1024] bf16
  unsigned short* Vt   = Q + 2 * SZ;

  // 1. prep: X->bf16, W->Wt (bf16, transposed), lvec=0
  k_prep<<<dim3(17153), 256, 0, stream>>>(X, Xb, Wq, Wk, Wv, Wt, lvec);

  // 2. fused QKV projection (24 n-strips: 8 Q, 8 K, 8 V), B direct from L2
  k_gemm<4><<<dim3(128, 24, 1), 256, 0, stream>>>(
      Xb, Wt, (void*)Q, bq, bk, bv, nullptr, nullptr, nullptr,
      0, 0, 1024, 1024, 16);

  // 3. P = exp(Q K^T) masked + atomic row sums
  k_gemm<2><<<dim3(16, 16, 8), 256, 0, stream>>>(
      Q, Q + SZ, (void*)P, nullptr, nullptr, nullptr, nullptr, lvec, mask,
      2048 * 1024, 2048 * 1024, 1024, 1024, 16);

  // 4. O = (P V) / l  -> fp32 out
  k_gemm<3><<<dim3(16, 8, 8), 256, 0, stream>>>(
      P, Vt, (void*)out, nullptr, nullptr, nullptr, lvec, nullptr, nullptr,
      2048 * 2048, 1024 * 2048, 2048, 2048, 32);
}

// Round 5
// 461.381 us; speedup vs baseline: 1.1846x; 1.1846x over previous
//
#include <hip/hip_runtime.h>
#include <stdint.h>

#define DEVI __device__ __forceinline__

typedef __bf16 bf16x8 __attribute__((ext_vector_type(8)));
typedef float  floatx4 __attribute__((ext_vector_type(4)));

// B=8, S=2048, H=1024. M = B*S = 16384.
// ws: Q @0 (32MiB, pre-scaled 1/32) | K @+32M | Vt @+64M ([8][1024 d][2048 k])
//     lvec @+96M (f32[16384]) | P @+96M+64K (bf16 [8][2048][2048]);
//     P region overlays Xb (32MiB) + Wt (6MiB), dead before P written.

DEVI unsigned short f2bf(float f) {
  union { float f; uint32_t u; } x; x.f = f;
  return (unsigned short)((x.u + 0x7fffu + ((x.u >> 16) & 1u)) >> 16);
}
DEVI float bf2f(unsigned short s) {
  union { uint32_t u; float f; } x; x.u = ((uint32_t)s) << 16;
  return x.f;
}

// ---------------- fused prep: X->bf16, 3x W transpose->bf16, lvec=0 ----------------
__global__ __launch_bounds__(256) void k_prep(
    const float* __restrict__ X, unsigned short* __restrict__ Xb,
    const float* __restrict__ Wq, const float* __restrict__ Wk,
    const float* __restrict__ Wv, unsigned short* __restrict__ Wt,
    float* __restrict__ lvec) {
  __shared__ float tile[64][65];
  int bx = blockIdx.x, t = threadIdx.x;
  if (bx < 16384) {                 // convert X: 4194304 float4 groups
    int i = bx * 256 + t;
    float4 v = ((const float4*)X)[i];
    ushort4 o;
    o.x = f2bf(v.x); o.y = f2bf(v.y); o.z = f2bf(v.z); o.w = f2bf(v.w);
    ((ushort4*)Xb)[i] = o;
  } else if (bx < 17152) {          // 3 x 256 transpose blocks
    int idx = bx - 16384;
    int sel = idx >> 8, b2 = idx & 255;
    const float* W = sel == 0 ? Wq : (sel == 1 ? Wk : Wv);
    unsigned short* Wo = Wt + ((size_t)sel << 20);
    int h0 = (b2 & 15) * 64, d0 = (b2 >> 4) * 64;
#pragma unroll
    for (int i = 0; i < 16; ++i) {
      int idx2 = i * 256 + t; int r = idx2 >> 6, c = idx2 & 63;
      tile[r][c] = W[(size_t)(h0 + r) * 1024 + d0 + c];
    }
    __syncthreads();
#pragma unroll
    for (int i = 0; i < 16; ++i) {
      int idx2 = i * 256 + t; int r = idx2 >> 6, c = idx2 & 63;
      Wo[(size_t)(d0 + r) * 1024 + h0 + c] = f2bf(tile[c][r]);
    }
  } else {                          // zero lvec (16384 f32)
    float4 z4 = {0.f, 0.f, 0.f, 0.f};
#pragma unroll
    for (int i = 0; i < 16; ++i) ((float4*)lvec)[i * 256 + t] = z4;
  }
}

// ---------------- async 16B global -> LDS ----------------
DEVI void gl_lds16(const unsigned short* gp, unsigned short* lp) {
  __builtin_amdgcn_global_load_lds(
      (const __attribute__((address_space(1))) void*)gp,
      (__attribute__((address_space(3))) void*)lp, 16, 0, 0);
}

// ---------------- C = A * Bt^T  (both bf16 row-major, K-major rows) ----------------
// 128x128 tile, BK=64, 4 waves, 16x MFMA 16x16x32 per wave quadrant.
// LDS 16B-unit XOR swizzle c' = c ^ (row&7). (Round-2 core: do NOT replace
// with 32x32 MFMA or LDS-staged epilogue or B-direct loads — all measured
// regressions, rounds 3/4.)
// EPI: 4 = fused QKV (sel=blockIdx.y>>3): Q (x+b)/32, K x+b, V -> Vt[b][d][k]
//      2 = P = exp(S) masked, bf16; atomic row sums -> lsum
//      3 = O = (P*V) * 1/lvec[row], f32
template <int EPI>
__global__ __launch_bounds__(256) void k_gemm(
    const unsigned short* __restrict__ A, const unsigned short* __restrict__ Bt,
    void* __restrict__ Cv,
    const float* __restrict__ bias_q, const float* __restrict__ bias_k,
    const float* __restrict__ bias_v,
    const float* __restrict__ lvec, float* __restrict__ lsum,
    const int* __restrict__ mask,
    long aZ, long bZ, int ldA, int ldB, int kIters)
{
  __shared__ unsigned short As[128 * 64];
  __shared__ unsigned short Bs[128 * 64];
  const int t = threadIdx.x, w = t >> 6, l = t & 63;
  const int quad = l >> 4, l15 = l & 15;
  const int m0 = blockIdx.x * 128;
  const int z = blockIdx.z;
  const int wm = (w & 1) * 64, wn = (w >> 1) * 64;

  int n0, sel = 0;
  if constexpr (EPI == 4) { sel = blockIdx.y >> 3; n0 = (blockIdx.y & 7) * 128; }
  else n0 = blockIdx.y * 128;

  const unsigned short* Az = A + (size_t)z * aZ;
  const unsigned short* Bz = (EPI == 4) ? (Bt + ((size_t)sel << 20))
                                        : (Bt + (size_t)z * bZ);

  floatx4 acc[4][4];
#pragma unroll
  for (int i = 0; i < 4; ++i)
#pragma unroll
    for (int j = 0; j < 4; ++j) { floatx4 zz = {0.f, 0.f, 0.f, 0.f}; acc[i][j] = zz; }

  for (int kt = 0; kt < kIters; ++kt) {
    __syncthreads();
#pragma unroll
    for (int i = 0; i < 4; ++i) {
      int u   = (i * 4 + w) * 64 + l;   // 16B-unit index in [0,1024)
      int row = u >> 3;
      int cc  = (u & 7) ^ (row & 7);
      gl_lds16(Az + (size_t)(m0 + row) * ldA + kt * 64 + cc * 8,
               &As[(i * 4 + w) * 512]);
      gl_lds16(Bz + (size_t)(n0 + row) * ldB + kt * 64 + cc * 8,
               &Bs[(i * 4 + w) * 512]);
    }
    __syncthreads();
#pragma unroll
    for (int ks = 0; ks < 2; ++ks) {
      bf16x8 af[4], bfr[4];
#pragma unroll
      for (int ms = 0; ms < 4; ++ms) {
        int r  = wm + ms * 16 + l15;          // A[m=lane&15][k=quad*8+j]
        int cc = (ks * 4 + quad) ^ (r & 7);
        af[ms] = *(const bf16x8*)&As[r * 64 + cc * 8];
      }
#pragma unroll
      for (int ns = 0; ns < 4; ++ns) {
        int r  = wn + ns * 16 + l15;          // B symmetric
        int cc = (ks * 4 + quad) ^ (r & 7);
        bfr[ns] = *(const bf16x8*)&Bs[r * 64 + cc * 8];
      }
#pragma unroll
      for (int ms = 0; ms < 4; ++ms)
#pragma unroll
        for (int ns = 0; ns < 4; ++ns)
          acc[ms][ns] = __builtin_amdgcn_mfma_f32_16x16x32_bf16(
              af[ms], bfr[ns], acc[ms][ns], 0, 0, 0);
    }
  }

  // epilogue: C/D layout col = lane&15, row = quad*4 + reg  [m89/m91]
  if constexpr (EPI == 4) {
    unsigned short* C = (unsigned short*)Cv + ((size_t)sel << 24);
    const float* bs = sel == 0 ? bias_q : (sel == 1 ? bias_k : bias_v);
    if (sel < 2) {
      float sc = sel == 0 ? 0.03125f : 1.0f;
#pragma unroll
      for (int ns = 0; ns < 4; ++ns) {
        int n_g = n0 + wn + ns * 16 + l15;
        float bv = bs[n_g];
#pragma unroll
        for (int ms = 0; ms < 4; ++ms) {
          int mb = m0 + wm + ms * 16 + quad * 4;
#pragma unroll
          for (int r = 0; r < 4; ++r)
            C[(size_t)(mb + r) * 1024 + n_g] = f2bf((acc[ms][ns][r] + bv) * sc);
        }
      }
    } else {
      // V -> Vt[b][d][k]: the 4 r-values are CONSECUTIVE in k -> pack 8B stores
#pragma unroll
      for (int ns = 0; ns < 4; ++ns) {
        int n_g = n0 + wn + ns * 16 + l15;
        float bv = bs[n_g];
#pragma unroll
        for (int ms = 0; ms < 4; ++ms) {
          int m_g = m0 + wm + ms * 16 + quad * 4;   // r=0 element
          int bb = m_g >> 11, key = m_g & 2047;
          ushort4 pk;
          pk.x = f2bf(acc[ms][ns][0] + bv);
          pk.y = f2bf(acc[ms][ns][1] + bv);
          pk.z = f2bf(acc[ms][ns][2] + bv);
          pk.w = f2bf(acc[ms][ns][3] + bv);
          *(ushort4*)&C[((size_t)bb << 21) + ((size_t)n_g << 11) + key] = pk;
        }
      }
    }
  } else if constexpr (EPI == 2) {
    // P = exp(S) (max-free: |S| <= ~6), masked; atomic rowsums
    unsigned short* C = (unsigned short*)Cv + (size_t)z * 4194304;
    const int* mz = mask + z * 2048;
    float rowsum[4][4];
#pragma unroll
    for (int ms = 0; ms < 4; ++ms)
#pragma unroll
      for (int r = 0; r < 4; ++r) rowsum[ms][r] = 0.f;
#pragma unroll
    for (int ns = 0; ns < 4; ++ns) {
      int n_g = n0 + wn + ns * 16 + l15;
      int mv = mz[n_g];
#pragma unroll
      for (int ms = 0; ms < 4; ++ms) {
#pragma unroll
        for (int r = 0; r < 4; ++r) {
          int m_g = m0 + wm + ms * 16 + quad * 4 + r;
          float e = mv ? __expf(acc[ms][ns][r]) : 0.f;
          unsigned short pb = f2bf(e);
          C[(size_t)m_g * 2048 + n_g] = pb;
          rowsum[ms][r] += bf2f(pb);
        }
      }
    }
#pragma unroll
    for (int ms = 0; ms < 4; ++ms) {
#pragma unroll
      for (int r = 0; r < 4; ++r) {
        float s = rowsum[ms][r];
#pragma unroll
        for (int off = 1; off < 16; off <<= 1) s += __shfl_xor(s, off);
        if (l15 == 0) {
          int m_g = m0 + wm + ms * 16 + quad * 4 + r;
          atomicAdd(&lsum[z * 2048 + m_g], s);
        }
      }
    }
  } else {  // EPI == 3: O = (P*V)/l
    float* C = (float*)Cv + (size_t)z * 2048 * 1024;
    const float* lz = lvec + z * 2048;
#pragma unroll
    for (int ms = 0; ms < 4; ++ms) {
#pragma unroll
      for (int r = 0; r < 4; ++r) {
        int m_g = m0 + wm + ms * 16 + quad * 4 + r;
        float lw = lz[m_g];
        float inv = lw > 0.f ? 1.f / lw : 0.f;
#pragma unroll
        for (int ns = 0; ns < 4; ++ns) {
          int n_g = n0 + wn + ns * 16 + l15;
          C[(size_t)m_g * 1024 + n_g] = acc[ms][ns][r] * inv;
        }
      }
    }
  }
}

extern "C" void kernel_launch(void* const* d_in, const int* in_sizes, int n_in,
                              void* d_out, int out_size, void* d_ws, size_t ws_size,
                              hipStream_t stream) {
  const float* X    = (const float*)d_in[0];
  const int*   mask = (const int*)d_in[1];
  const float* Wq   = (const float*)d_in[2];
  const float* bq   = (const float*)d_in[3];
  const float* Wk   = (const float*)d_in[4];
  const float* bk   = (const float*)d_in[5];
  const float* Wv   = (const float*)d_in[6];
  const float* bv   = (const float*)d_in[7];
  float* out = (float*)d_out;

  constexpr size_t SZ = (size_t)16384 * 1024;
  unsigned short* Q    = (unsigned short*)d_ws;      // Q|K|Vt contiguous (sel<<24)
  float*          lvec = (float*)(Q + 3 * SZ);
  unsigned short* P    = (unsigned short*)(lvec + 16384);
  unsigned short* Xb   = P;               // overlaid: dead before P written
  unsigned short* Wt   = Xb + SZ;         // 3 x [1024][1024] bf16
  unsigned short* Vt   = Q + 2 * SZ;

  // 1. prep: X->bf16, W->Wt (bf16, transposed), lvec=0
  k_prep<<<dim3(17153), 256, 0, stream>>>(X, Xb, Wq, Wk, Wv, Wt, lvec);

  // 2. fused QKV projection (24 n-strips: 8 Q, 8 K, 8 V)
  k_gemm<4><<<dim3(128, 24, 1), 256, 0, stream>>>(
      Xb, Wt, (void*)Q, bq, bk, bv, nullptr, nullptr, nullptr,
      0, 0, 1024, 1024, 16);

  // 3. P = exp(Q K^T) masked + atomic row sums
  k_gemm<2><<<dim3(16, 16, 8), 256, 0, stream>>>(
      Q, Q + SZ, (void*)P, nullptr, nullptr, nullptr, nullptr, lvec, mask,
      2048 * 1024, 2048 * 1024, 1024, 1024, 16);

  // 4. O = (P V) / l  -> fp32 out
  k_gemm<3><<<dim3(16, 8, 8), 256, 0, stream>>>(
      P, Vt, (void*)out, nullptr, nullptr, nullptr, lvec, nullptr, nullptr,
      2048 * 2048, 1024 * 2048, 2048, 2048, 32);
}